// Round 5
// baseline (433.072 us; speedup 1.0000x reference)
//
#include <hip/hip_runtime.h>

#define EPS 1e-10f
#define FAR_DELTA 1e10f

typedef float f32x4 __attribute__((ext_vector_type(4)));

// Thread-per-ray serial scan. No cross-lane ops, no LDS, no barriers.
// 16 batches x 8 samples, software-pipelined: batch b+1's 10 dwordx4 loads
// issue before batch b's compute. Each load instruction spans 64 distinct
// 128B lines (512B ray stride across lanes) -> maximal miss-issue per instr.
// Density (always HBM-cold) loaded non-temporally to avoid evicting the
// L3-resident depth/feature streams.
__global__ __launch_bounds__(256) void volrend_kernel(
    const float* __restrict__ density,   // [N,128]
    const float* __restrict__ feature,   // [N,128,3]
    const float* __restrict__ depth,     // [N,128]
    float* __restrict__ feat_out,        // [N,3]
    float* __restrict__ depth_out,       // [N]
    int N)
{
    const int ray = blockIdx.x * 256 + threadIdx.x;
    if (ray >= N) return;

    const f32x4* d4 = (const f32x4*)(density + (size_t)ray * 128);
    const f32x4* z4 = (const f32x4*)(depth   + (size_t)ray * 128);
    const f32x4* f4 = (const f32x4*)(feature + (size_t)ray * 384);

    // Current / next batch registers.
    f32x4 cd0, cd1, cz0, cz1, cf0, cf1, cf2, cf3, cf4, cf5;
    f32x4 nd0, nd1, nz0, nz1, nf0, nf1, nf2, nf3, nf4, nf5;

    // Prologue: batch 0.
    cd0 = __builtin_nontemporal_load(&d4[0]);
    cd1 = __builtin_nontemporal_load(&d4[1]);
    cz0 = z4[0]; cz1 = z4[1];
    cf0 = f4[0]; cf1 = f4[1]; cf2 = f4[2]; cf3 = f4[3]; cf4 = f4[4]; cf5 = f4[5];

    float trans = 1.0f;
    float a0 = 0.0f, a1 = 0.0f, a2 = 0.0f, ad = 0.0f;

    #pragma unroll
    for (int b = 0; b < 16; ++b) {
        // ---- prefetch batch b+1 (clamped; last iter re-loads batch 15) ----
        const int bn = (b < 15) ? (b + 1) : 15;
        nd0 = __builtin_nontemporal_load(&d4[bn * 2 + 0]);
        nd1 = __builtin_nontemporal_load(&d4[bn * 2 + 1]);
        nz0 = z4[bn * 2 + 0]; nz1 = z4[bn * 2 + 1];
        nf0 = f4[bn * 6 + 0]; nf1 = f4[bn * 6 + 1]; nf2 = f4[bn * 6 + 2];
        nf3 = f4[bn * 6 + 3]; nf4 = f4[bn * 6 + 4]; nf5 = f4[bn * 6 + 5];

        // ---- compute batch b ----
        float z[9]  = {cz0.x, cz0.y, cz0.z, cz0.w, cz1.x, cz1.y, cz1.z, cz1.w,
                       nz0.x};                       // z[8] unused when b==15
        float dn[8] = {cd0.x, cd0.y, cd0.z, cd0.w, cd1.x, cd1.y, cd1.z, cd1.w};
        float f[24] = {cf0.x, cf0.y, cf0.z, cf0.w, cf1.x, cf1.y, cf1.z, cf1.w,
                       cf2.x, cf2.y, cf2.z, cf2.w, cf3.x, cf3.y, cf3.z, cf3.w,
                       cf4.x, cf4.y, cf4.z, cf4.w, cf5.x, cf5.y, cf5.z, cf5.w};

        #pragma unroll
        for (int k = 0; k < 8; ++k) {
            float delta = (b == 15 && k == 7) ? FAR_DELTA : (z[k + 1] - z[k]);
            float ex = __expf(-fmaxf(dn[k], 0.0f) * delta);   // 1 - alpha
            float wk = (1.0f - ex) * trans;
            trans *= (ex + EPS);
            a0 += wk * f[3 * k + 0];
            a1 += wk * f[3 * k + 1];
            a2 += wk * f[3 * k + 2];
            ad += wk * z[k];
        }

        // ---- rotate ----
        cd0 = nd0; cd1 = nd1; cz0 = nz0; cz1 = nz1;
        cf0 = nf0; cf1 = nf1; cf2 = nf2; cf3 = nf3; cf4 = nf4; cf5 = nf5;
    }

    feat_out[(size_t)ray * 3 + 0] = a0;
    feat_out[(size_t)ray * 3 + 1] = a1;
    feat_out[(size_t)ray * 3 + 2] = a2;
    depth_out[ray] = ad;
}

extern "C" void kernel_launch(void* const* d_in, const int* in_sizes, int n_in,
                              void* d_out, int out_size, void* d_ws, size_t ws_size,
                              hipStream_t stream) {
    const float* density = (const float*)d_in[0];   // [N,128]
    const float* feature = (const float*)d_in[1];   // [N,128,3]
    const float* depth   = (const float*)d_in[2];   // [N,128]

    const int P = 128;
    const int N = in_sizes[0] / P;                  // 131072

    float* feat_out  = (float*)d_out;                 // [N,3]
    float* depth_out = (float*)d_out + (size_t)N * 3; // [N]

    dim3 grid((N + 255) / 256);                     // 512 blocks, 1 ray/thread
    dim3 block(256);
    volrend_kernel<<<grid, block, 0, stream>>>(density, feature, depth,
                                               feat_out, depth_out, N);
}